// Round 2
// baseline (14699.915 us; speedup 1.0000x reference)
//
#include <hip/hip_runtime.h>
#include <stdint.h>
#include <math.h>

// Bayesian STDP persistent-scan kernel, v2.
// - Cross-WG data (psp buffers, softmax stats, barrier) via relaxed AGENT-scope
//   atomics only -> no __threadfence (no buffer_wbl2/buffer_inv per step).
// - psp recurrence in registers (1 float/thread), published via agent stores.
// - Prefetch: GEMM1 psp fragments loaded right after the grid barrier for the
//   NEXT step; phase-D psp fragments + next spikes issued at step top.
// - W tile in LDS with 36-float chunk stride (4-way-floor bank conflicts).

#define TSTEPS 1000
#define BB     64
#define NINF   512
#define NOUTT  128
#define NG     32
#define NO     4
#define NTHR   1024
#define PSPD   0.9f
#define VD     0.9f
#define LRC    1e-3f

#define PSPN      (BB*NINF)                 // 32768 floats per psp buffer
#define STATS_OFF (3*PSPN)                  // [2][NG][BB][2] floats
#define CTRL_OFF  (STATS_OFF + 2*NG*BB*2)   // ints: arrv[NG], cnt

#define CH    36                            // padded chunk stride (floats)
#define WROW  (32*CH)                       // 1152 floats per W row

__device__ __forceinline__ void sync_lds() {
  // barrier that drains only LDS (lgkmcnt=0, vmcnt=63, expcnt=7) so global
  // prefetches stay in flight across it. imm = 0xC07F.
  asm volatile("" ::: "memory");
  __builtin_amdgcn_s_waitcnt(0xC07F);
  __builtin_amdgcn_s_barrier();
  asm volatile("" ::: "memory");
}

__device__ __forceinline__ float2 aload_f2(const float* p) {
  unsigned long long u = __hip_atomic_load((const unsigned long long*)p,
      __ATOMIC_RELAXED, __HIP_MEMORY_SCOPE_AGENT);
  float2 r;
  r.x = __uint_as_float((unsigned)u);
  r.y = __uint_as_float((unsigned)(u >> 32));
  return r;
}
__device__ __forceinline__ void astore_f2(float* p, float x, float y) {
  unsigned long long u = (unsigned long long)__float_as_uint(x)
                       | ((unsigned long long)__float_as_uint(y) << 32);
  __hip_atomic_store((unsigned long long*)p, u, __ATOMIC_RELAXED, __HIP_MEMORY_SCOPE_AGENT);
}
__device__ __forceinline__ void astore_f1(float* p, float x) {
  __hip_atomic_store(p, x, __ATOMIC_RELAXED, __HIP_MEMORY_SCOPE_AGENT);
}
__device__ __forceinline__ int aload_i(const int* p) {
  return __hip_atomic_load(p, __ATOMIC_RELAXED, __HIP_MEMORY_SCOPE_AGENT);
}

__global__ __launch_bounds__(NTHR)
void bstdp_kernel(const float* __restrict__ spikes,   // [T][B][NIN]
                  const float* __restrict__ weight,   // [NOUT][NIN]
                  const float* __restrict__ bias,     // [NOUT]
                  float* __restrict__ out,            // [T][B][NOUT] ++ [B][NOUT]
                  float* __restrict__ ws)
{
  const int g   = blockIdx.x;
  const int tid = threadIdx.x;

  float* pspb  = ws;                 // 3 * PSPN
  float* stats = ws + STATS_OFF;     // 2 * NG * BB * 2
  int*   ctrl  = (int*)(ws + CTRL_OFF);
  int*   arrv  = ctrl;               // [NG] slot barrier (0xAA poison < 1)
  int*   cnt   = ctrl + NG;          // monotone counter barrier

  __shared__ __align__(16) float WtS[NO*WROW];     // 18.4 KB padded W state
  __shared__ __align__(16) float part[4*NO*NINF];  // 32 KB post_pre partials
  __shared__ __align__(16) float uS[NO*BB];        // membrane [o][b]
  __shared__ __align__(16) float zT[BB*NO];        // z transposed [b][o]
  __shared__ float pmS[16];                        // per-wave pm partials [w][o]
  __shared__ float btS[NO];

  if (g == 0 && tid == 0) __hip_atomic_store(cnt, 0, __ATOMIC_RELAXED, __HIP_MEMORY_SCOPE_AGENT);

  // ---- prologue: W tile (padded), bias, u=0, psp(0) shard ----
  for (int e = tid; e < NO*NINF; e += NTHR) {
    int o = e >> 9, i = e & 511;
    WtS[o*WROW + (i>>4)*CH + (i&15)] = weight[g*(NO*NINF) + e];
  }
  if (tid < NO)    btS[tid] = bias[g*NO + tid];
  if (tid < NO*BB) uS[tid] = 0.0f;

  float pspR = spikes[g*NTHR + tid];               // psp(0) = s(0)
  astore_f1(pspb + g*NTHR + tid, pspR);

  // ---- slot barrier #0 (poison-safe), orders cnt=0 and psp(0) stores ----
  __syncthreads();                                  // drains vmcnt(0)
  if (tid == 0) __hip_atomic_store(&arrv[g], 1, __ATOMIC_RELAXED, __HIP_MEMORY_SCOPE_AGENT);
  if (tid < NG) {
    while (aload_i(&arrv[tid]) < 1) __builtin_amdgcn_s_sleep(2);
  }
  __syncthreads();

  const int bp = tid >> 5;      // 0..31 : batch rows (bp, bp+32)
  const int cc = tid & 31;      // 0..31 : 16-float i-chunk
  const int q4 = tid & 3;       // local o (tid<256)
  const int b4 = tid >> 2;      // batch row (tid<256)
  const int bh = tid >> 8;      // 0..3  : batch quarter (phase D)
  const int iq = tid & 255;     // i-pair index (phase D)

  // initial GEMM1 psp fragments (step 0 reads buffer 0)
  float p0f[16], p1f[16];
  {
    const float* r0 = pspb + bp*NINF + cc*16;
    const float* r1 = r0 + 32*NINF;
    #pragma unroll
    for (int j = 0; j < 8; ++j) {
      float2 v0 = aload_f2(r0 + 2*j);
      float2 v1 = aload_f2(r1 + 2*j);
      p0f[2*j] = v0.x; p0f[2*j+1] = v0.y;
      p1f[2*j] = v1.x; p1f[2*j+1] = v1.y;
    }
  }

  for (int t = 0; t < TSTEPS; ++t) {
    const float* bufT = pspb + (t % 3)*PSPN;
    const int sb = t & 1;

    // ---------- A: prefetch D-fragments + next spikes; GEMM1 ----------
    float2 Dp[16];
    {
      const float* base = bufT + (bh*16)*NINF + iq*2;
      #pragma unroll
      for (int bo = 0; bo < 16; ++bo) Dp[bo] = aload_f2(base + bo*NINF);
    }
    float spn = 0.0f;
    if (t + 1 < TSTEPS) spn = spikes[(size_t)(t+1)*PSPN + g*NTHR + tid];

    {
      float a0[NO] = {0.f,0.f,0.f,0.f};
      float a1[NO] = {0.f,0.f,0.f,0.f};
      #pragma unroll
      for (int o = 0; o < NO; ++o) {
        const float* wb = &WtS[o*WROW + cc*CH];
        #pragma unroll
        for (int j = 0; j < 16; ++j) {
          float w = wb[j];
          a0[o] = fmaf(p0f[j], w, a0[o]);
          a1[o] = fmaf(p1f[j], w, a1[o]);
        }
      }
      #pragma unroll
      for (int m = 1; m < 32; m <<= 1) {
        #pragma unroll
        for (int o = 0; o < NO; ++o) {
          a0[o] += __shfl_xor(a0[o], m);
          a1[o] += __shfl_xor(a1[o], m);
        }
      }
      if (cc == 0) {
        #pragma unroll
        for (int o = 0; o < NO; ++o) {
          uS[o*BB + bp]      = VD*uS[o*BB + bp]      + a0[o] + btS[o];
          uS[o*BB + bp + 32] = VD*uS[o*BB + bp + 32] + a1[o] + btS[o];
        }
      }
    }
    sync_lds();

    // ---------- B: local softmax stats (agent store) + psp recurrence ----------
    if (tid < BB) {
      float u0 = uS[0*BB+tid], u1 = uS[1*BB+tid], u2 = uS[2*BB+tid], u3 = uS[3*BB+tid];
      float mx = fmaxf(fmaxf(u0,u1), fmaxf(u2,u3));
      float ssum = expf(u0-mx)+expf(u1-mx)+expf(u2-mx)+expf(u3-mx);
      astore_f2(stats + ((size_t)(sb*NG + g)*BB + tid)*2, mx, ssum);
    }
    pspR = PSPD*pspR + spn;
    astore_f1(pspb + ((t+1)%3)*PSPN + g*NTHR + tid, pspR);
    __syncthreads();                       // drains vmcnt(0): stats+psp at MALL

    // ---------- grid barrier (monotone counter, agent scope, no fences) ----------
    if (tid == 0) {
      __hip_atomic_fetch_add(cnt, 1, __ATOMIC_RELAXED, __HIP_MEMORY_SCOPE_AGENT);
      const int target = NG*(t+1);
      while (aload_i(cnt) < target) __builtin_amdgcn_s_sleep(1);
    }
    __syncthreads();

    // ---------- C: prefetch next GEMM1 fragments; merge stats; z; pm ----------
    {
      const float* bufN = pspb + ((t+1)%3)*PSPN;
      const float* r0 = bufN + bp*NINF + cc*16;
      const float* r1 = r0 + 32*NINF;
      #pragma unroll
      for (int j = 0; j < 8; ++j) {
        float2 v0 = aload_f2(r0 + 2*j);
        float2 v1 = aload_f2(r1 + 2*j);
        p0f[2*j] = v0.x; p0f[2*j+1] = v0.y;
        p1f[2*j] = v1.x; p1f[2*j+1] = v1.y;
      }
    }
    if (tid < 256) {
      float M = -1e30f, S = 0.f;
      #pragma unroll
      for (int k = 0; k < 8; ++k) {
        int gg = q4*8 + k;
        float2 msv = aload_f2(stats + ((size_t)(sb*NG + gg)*BB + b4)*2);
        float Mn = fmaxf(M, msv.x);
        S = S*expf(M - Mn) + msv.y*expf(msv.x - Mn);
        M = Mn;
      }
      #pragma unroll
      for (int m = 1; m < 4; m <<= 1) {
        float Mo = __shfl_xor(M, m);
        float So = __shfl_xor(S, m);
        float Mn = fmaxf(M, Mo);
        S = S*expf(M - Mn) + So*expf(Mo - Mn);
        M = Mn;
      }
      float z = expf(uS[q4*BB + b4] - M) / S;
      zT[b4*NO + q4] = z;
      out[(size_t)t*(BB*NOUTT) + (size_t)b4*NOUTT + g*NO + q4] = z;
      // pm partials: reduce z over the 16 batch rows in this wave
      float v = z;
      #pragma unroll
      for (int m = 4; m < 64; m <<= 1) v += __shfl_xor(v, m);
      if ((tid & 63) < 4) pmS[(tid >> 6)*NO + q4] = v;
    }
    sync_lds();

    // ---------- D: post_pre partials (prefetched psp fragments) ----------
    {
      float ac[NO][2] = {};
      #pragma unroll
      for (int bo = 0; bo < 16; ++bo) {
        const float4 z4 = *(const float4*)&zT[(bh*16 + bo)*NO];
        const float2 pv = Dp[bo];
        ac[0][0] = fmaf(z4.x, pv.x, ac[0][0]); ac[0][1] = fmaf(z4.x, pv.y, ac[0][1]);
        ac[1][0] = fmaf(z4.y, pv.x, ac[1][0]); ac[1][1] = fmaf(z4.y, pv.y, ac[1][1]);
        ac[2][0] = fmaf(z4.z, pv.x, ac[2][0]); ac[2][1] = fmaf(z4.z, pv.y, ac[2][1]);
        ac[3][0] = fmaf(z4.w, pv.x, ac[3][0]); ac[3][1] = fmaf(z4.w, pv.y, ac[3][1]);
      }
      #pragma unroll
      for (int o = 0; o < NO; ++o) {
        *(float2*)&part[((bh*NO + o) << 9) + iq*2] = make_float2(ac[o][0], ac[o][1]);
      }
    }
    sync_lds();

    // ---------- E: W,b update (Nessler rule) ----------
    {
      const int idx0 = tid*2;
      const int o = idx0 >> 9, i0 = idx0 & 511;
      float pp0 = (part[idx0]   + part[idx0+2048]   + part[idx0+4096]   + part[idx0+6144])   * (1.0f/BB);
      float pp1 = (part[idx0+1] + part[idx0+1+2048] + part[idx0+1+4096] + part[idx0+1+6144]) * (1.0f/BB);
      float pm  = (pmS[o] + pmS[NO+o] + pmS[2*NO+o] + pmS[3*NO+o]) * (1.0f/BB);
      const int wi = o*WROW + (i0>>4)*CH + (i0&15);
      float w0 = WtS[wi], w1 = WtS[wi+1];
      WtS[wi]   = w0 + LRC*(expf(-w0)*pp0 - pm);
      WtS[wi+1] = w1 + LRC*(expf(-w1)*pp1 - pm);
      if (tid < NO) {
        float bv = btS[tid];
        float pmb = (pmS[tid] + pmS[NO+tid] + pmS[2*NO+tid] + pmS[3*NO+tid]) * (1.0f/BB);
        btS[tid] = bv + LRC*(expf(-bv) - 1.0f)*pmb;
      }
    }
    sync_lds();
  }

  // ---- epilogue: u_final ----
  if (tid < 256) {
    out[(size_t)TSTEPS*(BB*NOUTT) + (size_t)b4*NOUTT + g*NO + q4] = uS[q4*BB + b4];
  }
}

extern "C" void kernel_launch(void* const* d_in, const int* in_sizes, int n_in,
                              void* d_out, int out_size, void* d_ws, size_t ws_size,
                              hipStream_t stream) {
  const float* spikes = (const float*)d_in[0];   // [1000,64,512] fp32
  const float* weight = (const float*)d_in[1];   // [128,512] fp32
  const float* bias   = (const float*)d_in[2];   // [128] fp32
  float* out = (float*)d_out;                    // [1000*64*128] ++ [64*128]
  float* ws  = (float*)d_ws;

  bstdp_kernel<<<dim3(NG), dim3(NTHR), 0, stream>>>(spikes, weight, bias, out, ws);
}

// Round 3
// 14293.750 us; speedup vs baseline: 1.0284x; 1.0284x over previous
//
#include <hip/hip_runtime.h>
#include <stdint.h>
#include <math.h>

// Bayesian STDP persistent-scan kernel, v3.
// v2 -> v3: grid barrier rebuilt as contention-free per-WG epoch flags
// (32 independent cache lines, all-WGs-poll-all via one 32-lane load +
// __ballot) replacing the single contended atomic counter (which serialized
// 32 cross-XCD RMW+invalidate rounds per step ~ 10us). z_out/u_final stores
// are now nontemporal (out lines are partially written by 8 XCDs).

#define TSTEPS 1000
#define BB     64
#define NINF   512
#define NOUTT  128
#define NG     32
#define NO     4
#define NTHR   1024
#define PSPD   0.9f
#define VD     0.9f
#define LRC    1e-3f

#define PSPN      (BB*NINF)                 // 32768 floats per psp buffer
#define STATS_OFF (3*PSPN)                  // [2][NG][BB][2] floats
#define CTRL_OFF  (STATS_OFF + 2*NG*BB*2)   // ints: flags[NG*32] (128B stride)

#define CH    36                            // padded chunk stride (floats)
#define WROW  (32*CH)                       // 1152 floats per W row

__device__ __forceinline__ void sync_lds() {
  // barrier draining only LDS (lgkmcnt=0, vmcnt=63, expcnt=7): global
  // prefetches stay in flight across it. imm = 0xC07F.
  asm volatile("" ::: "memory");
  __builtin_amdgcn_s_waitcnt(0xC07F);
  __builtin_amdgcn_s_barrier();
  asm volatile("" ::: "memory");
}

__device__ __forceinline__ float2 aload_f2(const float* p) {
  unsigned long long u = __hip_atomic_load((const unsigned long long*)p,
      __ATOMIC_RELAXED, __HIP_MEMORY_SCOPE_AGENT);
  float2 r;
  r.x = __uint_as_float((unsigned)u);
  r.y = __uint_as_float((unsigned)(u >> 32));
  return r;
}
__device__ __forceinline__ void astore_f2(float* p, float x, float y) {
  unsigned long long u = (unsigned long long)__float_as_uint(x)
                       | ((unsigned long long)__float_as_uint(y) << 32);
  __hip_atomic_store((unsigned long long*)p, u, __ATOMIC_RELAXED, __HIP_MEMORY_SCOPE_AGENT);
}
__device__ __forceinline__ void astore_f1(float* p, float x) {
  __hip_atomic_store(p, x, __ATOMIC_RELAXED, __HIP_MEMORY_SCOPE_AGENT);
}
__device__ __forceinline__ void astore_i(int* p, int v) {
  __hip_atomic_store(p, v, __ATOMIC_RELAXED, __HIP_MEMORY_SCOPE_AGENT);
}
__device__ __forceinline__ int aload_i(const int* p) {
  return __hip_atomic_load(p, __ATOMIC_RELAXED, __HIP_MEMORY_SCOPE_AGENT);
}

__global__ __launch_bounds__(NTHR)
void bstdp_kernel(const float* __restrict__ spikes,   // [T][B][NIN]
                  const float* __restrict__ weight,   // [NOUT][NIN]
                  const float* __restrict__ bias,     // [NOUT]
                  float* __restrict__ out,            // [T][B][NOUT] ++ [B][NOUT]
                  float* __restrict__ ws)
{
  const int g   = blockIdx.x;
  const int tid = threadIdx.x;

  float* pspb  = ws;                 // 3 * PSPN
  float* stats = ws + STATS_OFF;     // 2 * NG * BB * 2
  int*   flags = (int*)(ws + CTRL_OFF); // [NG][32] ints, one line per WG
                                        // poison 0xAAAAAAAA < 1: safe

  __shared__ __align__(16) float WtS[NO*WROW];     // 18.4 KB padded W state
  __shared__ __align__(16) float part[4*NO*NINF];  // 32 KB post_pre partials
  __shared__ __align__(16) float uS[NO*BB];        // membrane [o][b]
  __shared__ __align__(16) float zT[BB*NO];        // z transposed [b][o]
  __shared__ float pmS[16];                        // per-wave pm partials [w][o]
  __shared__ float btS[NO];

  // ---- prologue: W tile (padded), bias, u=0, psp(0) shard ----
  for (int e = tid; e < NO*NINF; e += NTHR) {
    int o = e >> 9, i = e & 511;
    WtS[o*WROW + (i>>4)*CH + (i&15)] = weight[g*(NO*NINF) + e];
  }
  if (tid < NO)    btS[tid] = bias[g*NO + tid];
  if (tid < NO*BB) uS[tid] = 0.0f;

  float pspR = spikes[g*NTHR + tid];               // psp(0) = s(0)
  astore_f1(pspb + g*NTHR + tid, pspR);

  // ---- grid barrier #0 (epoch 1): psp(0) published ----
  __syncthreads();                                  // drains vmcnt(0)
  if (tid == 0) astore_i(&flags[g*32], 1);
  if (tid < 64) {
    for (;;) {
      int v = (tid < NG) ? aload_i(&flags[tid*32]) : 0x7fffffff;
      if (~__ballot(v >= 1) == 0ULL) break;
      __builtin_amdgcn_s_sleep(1);
    }
  }
  __syncthreads();

  const int bp = tid >> 5;      // 0..31 : batch rows (bp, bp+32)
  const int cc = tid & 31;      // 0..31 : 16-float i-chunk
  const int q4 = tid & 3;       // local o (tid<256)
  const int b4 = tid >> 2;      // batch row (tid<256)
  const int bh = tid >> 8;      // 0..3  : batch quarter (phase D)
  const int iq = tid & 255;     // i-pair index (phase D)

  // initial GEMM1 psp fragments (step 0 reads buffer 0)
  float p0f[16], p1f[16];
  {
    const float* r0 = pspb + bp*NINF + cc*16;
    const float* r1 = r0 + 32*NINF;
    #pragma unroll
    for (int j = 0; j < 8; ++j) {
      float2 v0 = aload_f2(r0 + 2*j);
      float2 v1 = aload_f2(r1 + 2*j);
      p0f[2*j] = v0.x; p0f[2*j+1] = v0.y;
      p1f[2*j] = v1.x; p1f[2*j+1] = v1.y;
    }
  }

  for (int t = 0; t < TSTEPS; ++t) {
    const float* bufT = pspb + (t % 3)*PSPN;
    const int sb = t & 1;

    // ---------- A: prefetch D-fragments + next spikes; GEMM1 ----------
    float2 Dp[16];
    {
      const float* base = bufT + (bh*16)*NINF + iq*2;
      #pragma unroll
      for (int bo = 0; bo < 16; ++bo) Dp[bo] = aload_f2(base + bo*NINF);
    }
    float spn = 0.0f;
    if (t + 1 < TSTEPS) spn = spikes[(size_t)(t+1)*PSPN + g*NTHR + tid];

    {
      float a0[NO] = {0.f,0.f,0.f,0.f};
      float a1[NO] = {0.f,0.f,0.f,0.f};
      #pragma unroll
      for (int o = 0; o < NO; ++o) {
        const float* wb = &WtS[o*WROW + cc*CH];
        #pragma unroll
        for (int j = 0; j < 16; ++j) {
          float w = wb[j];
          a0[o] = fmaf(p0f[j], w, a0[o]);
          a1[o] = fmaf(p1f[j], w, a1[o]);
        }
      }
      #pragma unroll
      for (int m = 1; m < 32; m <<= 1) {
        #pragma unroll
        for (int o = 0; o < NO; ++o) {
          a0[o] += __shfl_xor(a0[o], m);
          a1[o] += __shfl_xor(a1[o], m);
        }
      }
      if (cc == 0) {
        #pragma unroll
        for (int o = 0; o < NO; ++o) {
          uS[o*BB + bp]      = VD*uS[o*BB + bp]      + a0[o] + btS[o];
          uS[o*BB + bp + 32] = VD*uS[o*BB + bp + 32] + a1[o] + btS[o];
        }
      }
    }
    sync_lds();

    // ---------- B: local softmax stats (agent store) + psp recurrence ----------
    if (tid < BB) {
      float u0 = uS[0*BB+tid], u1 = uS[1*BB+tid], u2 = uS[2*BB+tid], u3 = uS[3*BB+tid];
      float mx = fmaxf(fmaxf(u0,u1), fmaxf(u2,u3));
      float ssum = expf(u0-mx)+expf(u1-mx)+expf(u2-mx)+expf(u3-mx);
      astore_f2(stats + ((size_t)(sb*NG + g)*BB + tid)*2, mx, ssum);
    }
    pspR = PSPD*pspR + spn;
    astore_f1(pspb + ((t+1)%3)*PSPN + g*NTHR + tid, pspR);
    __syncthreads();                       // drains vmcnt(0): stats+psp visible

    // ---------- grid barrier: per-WG epoch flags, all-poll-all ----------
    if (tid == 0) astore_i(&flags[g*32], t + 2);
    if (tid < 64) {
      const int target = t + 2;
      for (;;) {
        int v = (tid < NG) ? aload_i(&flags[tid*32]) : 0x7fffffff;
        if (~__ballot(v >= target) == 0ULL) break;
        __builtin_amdgcn_s_sleep(1);
      }
    }
    __syncthreads();

    // ---------- C: prefetch next GEMM1 fragments; merge stats; z; pm ----------
    {
      const float* bufN = pspb + ((t+1)%3)*PSPN;
      const float* r0 = bufN + bp*NINF + cc*16;
      const float* r1 = r0 + 32*NINF;
      #pragma unroll
      for (int j = 0; j < 8; ++j) {
        float2 v0 = aload_f2(r0 + 2*j);
        float2 v1 = aload_f2(r1 + 2*j);
        p0f[2*j] = v0.x; p0f[2*j+1] = v0.y;
        p1f[2*j] = v1.x; p1f[2*j+1] = v1.y;
      }
    }
    if (tid < 256) {
      float M = -1e30f, S = 0.f;
      #pragma unroll
      for (int k = 0; k < 8; ++k) {
        int gg = q4*8 + k;
        float2 msv = aload_f2(stats + ((size_t)(sb*NG + gg)*BB + b4)*2);
        float Mn = fmaxf(M, msv.x);
        S = S*expf(M - Mn) + msv.y*expf(msv.x - Mn);
        M = Mn;
      }
      #pragma unroll
      for (int m = 1; m < 4; m <<= 1) {
        float Mo = __shfl_xor(M, m);
        float So = __shfl_xor(S, m);
        float Mn = fmaxf(M, Mo);
        S = S*expf(M - Mn) + So*expf(Mo - Mn);
        M = Mn;
      }
      float z = expf(uS[q4*BB + b4] - M) / S;
      zT[b4*NO + q4] = z;
      __builtin_nontemporal_store(z,
          out + (size_t)t*(BB*NOUTT) + (size_t)b4*NOUTT + g*NO + q4);
      // pm partials: reduce z over the 16 batch rows in this wave
      float v = z;
      #pragma unroll
      for (int m = 4; m < 64; m <<= 1) v += __shfl_xor(v, m);
      if ((tid & 63) < 4) pmS[(tid >> 6)*NO + q4] = v;
    }
    sync_lds();

    // ---------- D: post_pre partials (prefetched psp fragments) ----------
    {
      float ac[NO][2] = {};
      #pragma unroll
      for (int bo = 0; bo < 16; ++bo) {
        const float4 z4 = *(const float4*)&zT[(bh*16 + bo)*NO];
        const float2 pv = Dp[bo];
        ac[0][0] = fmaf(z4.x, pv.x, ac[0][0]); ac[0][1] = fmaf(z4.x, pv.y, ac[0][1]);
        ac[1][0] = fmaf(z4.y, pv.x, ac[1][0]); ac[1][1] = fmaf(z4.y, pv.y, ac[1][1]);
        ac[2][0] = fmaf(z4.z, pv.x, ac[2][0]); ac[2][1] = fmaf(z4.z, pv.y, ac[2][1]);
        ac[3][0] = fmaf(z4.w, pv.x, ac[3][0]); ac[3][1] = fmaf(z4.w, pv.y, ac[3][1]);
      }
      #pragma unroll
      for (int o = 0; o < NO; ++o) {
        *(float2*)&part[((bh*NO + o) << 9) + iq*2] = make_float2(ac[o][0], ac[o][1]);
      }
    }
    sync_lds();

    // ---------- E: W,b update (Nessler rule) ----------
    {
      const int idx0 = tid*2;
      const int o = idx0 >> 9, i0 = idx0 & 511;
      float pp0 = (part[idx0]   + part[idx0+2048]   + part[idx0+4096]   + part[idx0+6144])   * (1.0f/BB);
      float pp1 = (part[idx0+1] + part[idx0+1+2048] + part[idx0+1+4096] + part[idx0+1+6144]) * (1.0f/BB);
      float pm  = (pmS[o] + pmS[NO+o] + pmS[2*NO+o] + pmS[3*NO+o]) * (1.0f/BB);
      const int wi = o*WROW + (i0>>4)*CH + (i0&15);
      float w0 = WtS[wi], w1 = WtS[wi+1];
      WtS[wi]   = w0 + LRC*(expf(-w0)*pp0 - pm);
      WtS[wi+1] = w1 + LRC*(expf(-w1)*pp1 - pm);
      if (tid < NO) {
        float bv = btS[tid];
        float pmb = (pmS[tid] + pmS[NO+tid] + pmS[2*NO+tid] + pmS[3*NO+tid]) * (1.0f/BB);
        btS[tid] = bv + LRC*(expf(-bv) - 1.0f)*pmb;
      }
    }
    sync_lds();
  }

  // ---- epilogue: u_final ----
  if (tid < 256) {
    __builtin_nontemporal_store(uS[q4*BB + b4],
        out + (size_t)TSTEPS*(BB*NOUTT) + (size_t)b4*NOUTT + g*NO + q4);
  }
}

extern "C" void kernel_launch(void* const* d_in, const int* in_sizes, int n_in,
                              void* d_out, int out_size, void* d_ws, size_t ws_size,
                              hipStream_t stream) {
  const float* spikes = (const float*)d_in[0];   // [1000,64,512] fp32
  const float* weight = (const float*)d_in[1];   // [128,512] fp32
  const float* bias   = (const float*)d_in[2];   // [128] fp32
  float* out = (float*)d_out;                    // [1000*64*128] ++ [64*128]
  float* ws  = (float*)d_ws;

  bstdp_kernel<<<dim3(NG), dim3(NTHR), 0, stream>>>(spikes, weight, bias, out, ws);
}

// Round 4
// 11901.867 us; speedup vs baseline: 1.2351x; 1.2010x over previous
//
#include <hip/hip_runtime.h>
#include <stdint.h>
#include <math.h>

// Bayesian STDP persistent-scan kernel, v4: replicated-psp.
// Key change vs v3: NO cross-WG psp exchange. Each WG redundantly maintains
// the FULL psp trace [64][512] in its own LDS (padded rows, 132 KB), updated
// from normal cached spikes loads each step. Only cross-XCD data per step:
// softmax stats (16 KB total) + per-WG barrier flags. This removes the
// ~8 MB/step MALL-latency-bound exchange that capped v1-v3 at ~14 us/step.

#define TSTEPS 1000
#define BB     64
#define NINF   512
#define NOUTT  128
#define NG     32
#define NO     4
#define NTHR   1024
#define PSPD   0.9f
#define VD     0.9f
#define LRC    1e-3f
#define PS     516                  // padded row stride (floats), 16B-multiple

#define FLAGS_OFF (2*NG*BB*2)       // stats floats before flags

__device__ __forceinline__ void sync_lds() {
  // barrier draining only LDS (lgkmcnt=0, vmcnt=63, expcnt=7)
  asm volatile("" ::: "memory");
  __builtin_amdgcn_s_waitcnt(0xC07F);
  __builtin_amdgcn_s_barrier();
  asm volatile("" ::: "memory");
}

__device__ __forceinline__ float2 aload_f2(const float* p) {
  unsigned long long u = __hip_atomic_load((const unsigned long long*)p,
      __ATOMIC_RELAXED, __HIP_MEMORY_SCOPE_AGENT);
  float2 r;
  r.x = __uint_as_float((unsigned)u);
  r.y = __uint_as_float((unsigned)(u >> 32));
  return r;
}
__device__ __forceinline__ void astore_f2(float* p, float x, float y) {
  unsigned long long u = (unsigned long long)__float_as_uint(x)
                       | ((unsigned long long)__float_as_uint(y) << 32);
  __hip_atomic_store((unsigned long long*)p, u, __ATOMIC_RELAXED, __HIP_MEMORY_SCOPE_AGENT);
}
__device__ __forceinline__ void astore_i(int* p, int v) {
  __hip_atomic_store(p, v, __ATOMIC_RELAXED, __HIP_MEMORY_SCOPE_AGENT);
}
__device__ __forceinline__ int aload_i(const int* p) {
  return __hip_atomic_load(p, __ATOMIC_RELAXED, __HIP_MEMORY_SCOPE_AGENT);
}

__global__ __launch_bounds__(NTHR)
void bstdp_kernel(const float* __restrict__ spikes,   // [T][B][NIN]
                  const float* __restrict__ weight,   // [NOUT][NIN]
                  const float* __restrict__ bias,     // [NOUT]
                  float* __restrict__ out,            // [T][B][NOUT] ++ [B][NOUT]
                  float* __restrict__ ws)
{
  const int g   = blockIdx.x;
  const int tid = threadIdx.x;

  float* stats = ws;                       // [2][NG][BB][2] floats
  int*   flags = (int*)(ws + FLAGS_OFF);   // [NG][32] ints (poison 0xAA.. < 1)

  __shared__ __align__(16) float psp[BB*PS];   // 132 KB replicated psp trace
  __shared__ __align__(16) float Wt[NO*PS];    // 8.25 KB W tile (padded rows)
  __shared__ __align__(16) float zT[296];      // swizzled z [b][o]
  __shared__ __align__(16) float uS[NO*BB];    // membrane [o][b]
  __shared__ float pmS[16];                    // per-wave pm partials [w][o]
  __shared__ float btS[NO];

  // ---- prologue: W tile, bias, u=0, psp(0) = spikes(0) ----
  #pragma unroll
  for (int e = tid; e < NO*NINF; e += NTHR)
    Wt[(e>>9)*PS + (e&511)] = weight[g*(NO*NINF) + e];
  if (tid < NO)    btS[tid] = bias[g*NO + tid];
  if (tid < NO*BB) uS[tid] = 0.0f;
  #pragma unroll
  for (int k = 0; k < 8; ++k) {
    int j = tid*4 + k*4096;
    *(float4*)&psp[(j>>9)*PS + (j&511)] = *(const float4*)(spikes + j);
  }
  __syncthreads();

  const int bp = tid >> 5, cc = tid & 31;     // GEMM1: rows (bp, bp+32), chunk cc
  const int q4 = tid & 3,  b4 = tid >> 2;     // phase C (tid<256)
  const int dbh = tid & 3;                    // phase D: batch quarter
  const int di  = (tid >> 2) * 2;             // phase D: column pair

  for (int t = 0; t < TSTEPS; ++t) {
    const int sb = t & 1;

    // ---------- A: spikes(t+1) prefetch + GEMM1 from LDS ----------
    float4 spn[8];
    if (t + 1 < TSTEPS) {
      const float* sp = spikes + (size_t)(t+1)*(BB*NINF) + tid*4;
      #pragma unroll
      for (int k = 0; k < 8; ++k) spn[k] = *(const float4*)(sp + k*4096);
    }
    {
      float a0[NO] = {0.f,0.f,0.f,0.f};
      float a1[NO] = {0.f,0.f,0.f,0.f};
      const float* pr0 = &psp[bp*PS];
      const float* pr1 = &psp[(bp+32)*PS];
      #pragma unroll
      for (int k = 0; k < 4; ++k) {
        float4 p0 = *(const float4*)(pr0 + cc*4 + k*128);
        float4 p1 = *(const float4*)(pr1 + cc*4 + k*128);
        #pragma unroll
        for (int o = 0; o < NO; ++o) {
          float4 w = *(const float4*)(&Wt[o*PS + cc*4 + k*128]);
          a0[o] = fmaf(p0.x,w.x, fmaf(p0.y,w.y, fmaf(p0.z,w.z, fmaf(p0.w,w.w, a0[o]))));
          a1[o] = fmaf(p1.x,w.x, fmaf(p1.y,w.y, fmaf(p1.z,w.z, fmaf(p1.w,w.w, a1[o]))));
        }
      }
      #pragma unroll
      for (int m = 1; m < 32; m <<= 1) {
        #pragma unroll
        for (int o = 0; o < NO; ++o) {
          a0[o] += __shfl_xor(a0[o], m);
          a1[o] += __shfl_xor(a1[o], m);
        }
      }
      if (cc == 0) {
        #pragma unroll
        for (int o = 0; o < NO; ++o) {
          uS[o*BB + bp]      = VD*uS[o*BB + bp]      + a0[o] + btS[o];
          uS[o*BB + bp + 32] = VD*uS[o*BB + bp + 32] + a1[o] + btS[o];
        }
      }
    }
    sync_lds();

    // ---------- B: local softmax stats -> global (only cross-XCD write) ----------
    if (tid < BB) {
      float u0 = uS[0*BB+tid], u1 = uS[1*BB+tid], u2 = uS[2*BB+tid], u3 = uS[3*BB+tid];
      float mx = fmaxf(fmaxf(u0,u1), fmaxf(u2,u3));
      float ssum = expf(u0-mx)+expf(u1-mx)+expf(u2-mx)+expf(u3-mx);
      astore_f2(stats + ((size_t)(sb*NG + g)*BB + tid)*2, mx, ssum);
    }
    __syncthreads();                       // drains stats stores (vmcnt 0)

    // ---------- grid barrier: per-WG epoch flags ----------
    if (tid == 0) astore_i(&flags[g*32], t + 1);
    if (tid < 64) {
      const int target = t + 1;
      for (;;) {
        int v = (tid < NG) ? aload_i(&flags[tid*32]) : 0x7fffffff;
        if (~__ballot(v >= target) == 0ULL) break;
        __builtin_amdgcn_s_sleep(1);
      }
    }
    __syncthreads();

    // ---------- C: merge stats, z, out store, pm partials ----------
    if (tid < 256) {
      float M = -1e30f, S = 0.f;
      #pragma unroll
      for (int k = 0; k < 8; ++k) {
        int gg = q4*8 + k;
        float2 msv = aload_f2(stats + ((size_t)(sb*NG + gg)*BB + b4)*2);
        float Mn = fmaxf(M, msv.x);
        S = S*expf(M - Mn) + msv.y*expf(msv.x - Mn);
        M = Mn;
      }
      #pragma unroll
      for (int m = 1; m < 4; m <<= 1) {
        float Mo = __shfl_xor(M, m);
        float So = __shfl_xor(S, m);
        float Mn = fmaxf(M, Mo);
        S = S*expf(M - Mn) + So*expf(Mo - Mn);
        M = Mn;
      }
      float z = expf(uS[q4*BB + b4] - M) / S;
      zT[b4*4 + q4 + 4*(b4>>3)] = z;               // swizzled for phase D
      __builtin_nontemporal_store(z,
          out + (size_t)t*(BB*NOUTT) + (size_t)b4*NOUTT + g*NO + q4);
      float v = z;
      #pragma unroll
      for (int m = 4; m < 64; m <<= 1) v += __shfl_xor(v, m);
      if ((tid & 63) < 4) pmS[(tid >> 6)*NO + q4] = v;
    }
    sync_lds();

    // ---------- D/E: post_pre from LDS columns + W,b update ----------
    {
      float pp[NO][2] = {};
      #pragma unroll
      for (int r = 0; r < 16; ++r) {
        int b = dbh*16 + r;
        float2 pv = *(const float2*)&psp[b*PS + di];
        float4 z4 = *(const float4*)&zT[b*4 + 4*(b>>3)];
        pp[0][0] = fmaf(z4.x, pv.x, pp[0][0]); pp[0][1] = fmaf(z4.x, pv.y, pp[0][1]);
        pp[1][0] = fmaf(z4.y, pv.x, pp[1][0]); pp[1][1] = fmaf(z4.y, pv.y, pp[1][1]);
        pp[2][0] = fmaf(z4.z, pv.x, pp[2][0]); pp[2][1] = fmaf(z4.z, pv.y, pp[2][1]);
        pp[3][0] = fmaf(z4.w, pv.x, pp[3][0]); pp[3][1] = fmaf(z4.w, pv.y, pp[3][1]);
      }
      // combine the 4 batch-quarters (lanes differing in tid&3)
      #pragma unroll
      for (int m = 1; m < 4; m <<= 1) {
        #pragma unroll
        for (int o = 0; o < NO; ++o) {
          pp[o][0] += __shfl_xor(pp[o][0], m);
          pp[o][1] += __shfl_xor(pp[o][1], m);
        }
      }
      // lane with dbh==o updates W[o][di], W[o][di+1]
      float ppx, ppy;
      switch (dbh) {
        case 0: ppx = pp[0][0]; ppy = pp[0][1]; break;
        case 1: ppx = pp[1][0]; ppy = pp[1][1]; break;
        case 2: ppx = pp[2][0]; ppy = pp[2][1]; break;
        default: ppx = pp[3][0]; ppy = pp[3][1]; break;
      }
      float pm = (pmS[dbh] + pmS[NO+dbh] + pmS[2*NO+dbh] + pmS[3*NO+dbh]) * (1.0f/BB);
      float* wp = &Wt[dbh*PS + di];
      float w0 = wp[0], w1 = wp[1];
      wp[0] = w0 + LRC*(expf(-w0)*ppx*(1.0f/BB) - pm);
      wp[1] = w1 + LRC*(expf(-w1)*ppy*(1.0f/BB) - pm);
      if (tid < NO) {
        float pmb = (pmS[tid] + pmS[NO+tid] + pmS[2*NO+tid] + pmS[3*NO+tid]) * (1.0f/BB);
        float bv = btS[tid];
        btS[tid] = bv + LRC*(expf(-bv) - 1.0f)*pmb;
      }
    }
    sync_lds();

    // ---------- F: psp recurrence (in-place, LDS-local) ----------
    if (t + 1 < TSTEPS) {
      #pragma unroll
      for (int k = 0; k < 8; ++k) {
        int j = tid*4 + k*4096;
        float* pa = &psp[(j>>9)*PS + (j&511)];
        float4 p = *(float4*)pa;
        p.x = PSPD*p.x + spn[k].x;
        p.y = PSPD*p.y + spn[k].y;
        p.z = PSPD*p.z + spn[k].z;
        p.w = PSPD*p.w + spn[k].w;
        *(float4*)pa = p;
      }
    }
    sync_lds();
  }

  // ---- epilogue: u_final ----
  if (tid < 256) {
    __builtin_nontemporal_store(uS[q4*BB + b4],
        out + (size_t)TSTEPS*(BB*NOUTT) + (size_t)b4*NOUTT + g*NO + q4);
  }
}

extern "C" void kernel_launch(void* const* d_in, const int* in_sizes, int n_in,
                              void* d_out, int out_size, void* d_ws, size_t ws_size,
                              hipStream_t stream) {
  const float* spikes = (const float*)d_in[0];   // [1000,64,512] fp32
  const float* weight = (const float*)d_in[1];   // [128,512] fp32
  const float* bias   = (const float*)d_in[2];   // [128] fp32
  float* out = (float*)d_out;                    // [1000*64*128] ++ [64*128]
  float* ws  = (float*)d_ws;

  bstdp_kernel<<<dim3(NG), dim3(NTHR), 0, stream>>>(spikes, weight, bias, out, ws);
}